// Round 1
// baseline (89.135 us; speedup 1.0000x reference)
//
#include <hip/hip_runtime.h>
#include <math.h>

// ws float layout
#define WS_MSE  0
#define WS_TC   1
#define WS_OUT  2
#define WS_ORTH 3
#define WS_CENT 16   // C*L normalized centers start here

__device__ __forceinline__ float waveReduceSum(float v) {
    #pragma unroll
    for (int off = 32; off > 0; off >>= 1) v += __shfl_xor(v, off, 64);
    return v;
}

// One block, C waves (wave c owns center row c). Normalizes rows, writes
// normalized centers to ws[WS_CENT..], computes ||C C^T - I||_F^2 -> ws[WS_ORTH].
__global__ void centers_orth_kernel(const float* __restrict__ center_arr,
                                    float* __restrict__ ws, int C, int L) {
    extern __shared__ float sm[];  // C*L floats
    const int wave = threadIdx.x >> 6;
    const int lane = threadIdx.x & 63;
    const int epl  = L >> 6;       // elements per lane (2 for L=128)

    float vals[4];
    float ss = 0.f;
    #pragma unroll 4
    for (int e = 0; e < epl; ++e) {
        vals[e] = center_arr[wave * L + lane * epl + e];
        ss += vals[e] * vals[e];
    }
    ss = waveReduceSum(ss);
    const float inv = rsqrtf(ss);
    #pragma unroll 4
    for (int e = 0; e < epl; ++e) {
        const float nv = vals[e] * inv;
        sm[wave * L + lane * epl + e] = nv;
        ws[WS_CENT + wave * L + lane * epl + e] = nv;
    }
    __syncthreads();

    __shared__ float orth_acc;
    if (threadIdx.x == 0) orth_acc = 0.f;
    __syncthreads();

    float rowsum = 0.f;
    for (int cc = 0; cc < C; ++cc) {
        float d = 0.f;
        #pragma unroll 4
        for (int e = 0; e < epl; ++e)
            d += sm[wave * L + lane * epl + e] * sm[cc * L + lane * epl + e];
        d = waveReduceSum(d);
        const float t = d - (cc == wave ? 1.f : 0.f);
        rowsum += t * t;
    }
    if (lane == 0) atomicAdd(&orth_acc, rowsum);
    __syncthreads();
    if (threadIdx.x == 0) ws[WS_ORTH] = orth_acc;
}

// Grid-stride float4 sum of (x - x_hat)^2 -> atomicAdd ws[WS_MSE]
__global__ void mse_kernel(const float4* __restrict__ x,
                           const float4* __restrict__ xh,
                           float* __restrict__ ws, long n4) {
    long i = (long)blockIdx.x * blockDim.x + threadIdx.x;
    const long stride = (long)gridDim.x * blockDim.x;
    float acc = 0.f;
    for (; i < n4; i += stride) {
        const float4 a = x[i], b = xh[i];
        const float d0 = a.x - b.x, d1 = a.y - b.y;
        const float d2 = a.z - b.z, d3 = a.w - b.w;
        acc += d0 * d0 + d1 * d1 + d2 * d2 + d3 * d3;
    }
    acc = waveReduceSum(acc);
    __shared__ float smw[8];
    const int lane = threadIdx.x & 63, wave = threadIdx.x >> 6;
    if (lane == 0) smw[wave] = acc;
    __syncthreads();
    if (threadIdx.x == 0) {
        float s = 0.f;
        const int nw = blockDim.x >> 6;
        for (int w = 0; w < nw; ++w) s += smw[w];
        atomicAdd(&ws[WS_MSE], s);
    }
}

// One wave per row: triplet-center term + outlier term.
__global__ void tc_out_kernel(const float* __restrict__ z_in,
                              const float* __restrict__ z_out,
                              const int* __restrict__ target,
                              const float* __restrict__ ws_cent,
                              float* __restrict__ ws,
                              int B, int C, int L, float d_in, float d_out) {
    extern __shared__ float smc[];  // C*L centers
    const int tid = threadIdx.x;
    const int CL = C * L;
    for (int i = tid; i < CL; i += blockDim.x) smc[i] = ws_cent[i];
    __syncthreads();

    const int wave = tid >> 6, lane = tid & 63;
    const int row = blockIdx.x * (blockDim.x >> 6) + wave;
    float tc = 0.f, ol = 0.f;
    if (row < B) {
        const int epl = L >> 6;
        float zi[4], zo[4];
        #pragma unroll 4
        for (int e = 0; e < epl; ++e) {
            zi[e] = z_in[row * L + lane * epl + e];
            zo[e] = z_out[row * L + lane * epl + e];
        }
        const int tgt = target[row];
        float pos = 0.f, neg = INFINITY;
        for (int c = 0; c < C; ++c) {
            float d2 = 0.f;
            #pragma unroll 4
            for (int e = 0; e < epl; ++e) {
                const float diff = zi[e] - smc[c * L + lane * epl + e];
                d2 += diff * diff;
            }
            d2 = waveReduceSum(d2);
            const float dist = sqrtf(d2);
            if (c == tgt) pos = dist;
            else          neg = fminf(neg, dist);
        }
        tc = fmaxf(pos + d_in - neg, 0.f);
        float zo2 = 0.f;
        #pragma unroll 4
        for (int e = 0; e < epl; ++e) zo2 += zo[e] * zo[e];
        zo2 = waveReduceSum(zo2);
        ol = fmaxf(d_out - sqrtf(zo2), 0.f);
    }
    __shared__ float stc[8], sol[8];
    if (lane == 0) { stc[wave] = tc; sol[wave] = ol; }
    __syncthreads();
    if (tid == 0) {
        float a = 0.f, b = 0.f;
        const int nw = blockDim.x >> 6;
        for (int w = 0; w < nw; ++w) { a += stc[w]; b += sol[w]; }
        atomicAdd(&ws[WS_TC], a);
        atomicAdd(&ws[WS_OUT], b);
    }
}

__global__ void final_kernel(const float* __restrict__ ws, float* __restrict__ out,
                             float invBD, float invB) {
    out[0] = ws[WS_MSE] * invBD
           + ws[WS_TC]  * invB          // LAMBDA_TC = 1
           + ws[WS_OUT] * invB          // LAMBDA_OUT = 1
           + sqrtf(ws[WS_ORTH]);        // LAMBDA_CENT = 1
}

extern "C" void kernel_launch(void* const* d_in, const int* in_sizes, int n_in,
                              void* d_out, int out_size, void* d_ws, size_t ws_size,
                              hipStream_t stream) {
    const float* x          = (const float*)d_in[0];
    const float* x_hat      = (const float*)d_in[1];
    const int*   target     = (const int*)d_in[2];
    const float* z_in       = (const float*)d_in[3];
    const float* z_out      = (const float*)d_in[4];
    const float* center_arr = (const float*)d_in[5];
    float* out = (float*)d_out;
    float* ws  = (float*)d_ws;

    const int B = in_sizes[2];
    const int D = in_sizes[0] / B;
    const int L = in_sizes[3] / B;
    const int C = in_sizes[5] / L;

    // zero the accumulators (d_ws is poisoned 0xAA, never re-poisoned between replays)
    hipMemsetAsync(d_ws, 0, 16 * sizeof(float), stream);

    // 1) normalized centers + orthogonality loss (1 block, C waves)
    centers_orth_kernel<<<1, C * 64, C * L * sizeof(float), stream>>>(center_arr, ws, C, L);

    // 2) MSE partials (dominant: ~100 MB traffic)
    const long n4 = (long)B * D / 4;
    mse_kernel<<<2048, 256, 0, stream>>>((const float4*)x, (const float4*)x_hat, ws, n4);

    // 3) triplet-center + outlier partials (one wave per row)
    const int rpb = 4;  // rows per block (4 waves)
    tc_out_kernel<<<(B + rpb - 1) / rpb, rpb * 64, C * L * sizeof(float), stream>>>(
        z_in, z_out, target, ws + WS_CENT, ws, B, C, L, 0.1f, 1.0f);

    // 4) combine
    final_kernel<<<1, 1, 0, stream>>>(ws, out, 1.f / ((float)B * D), 1.f / (float)B);
}

// Round 2
// 44.788 us; speedup vs baseline: 1.9902x; 1.9902x over previous
//
#include <hip/hip_runtime.h>
#include <math.h>

#define D_IN_M   0.1f
#define D_OUT_M  1.0f

__device__ __forceinline__ float waveReduceSum(float v) {
    #pragma unroll
    for (int off = 32; off > 0; off >>= 1) v += __shfl_xor(v, off, 64);
    return v;
}

// Single fused kernel.
//  - every block stages + normalizes centers (C*L floats) in LDS
//  - waves of blocks [0, B/4) each handle one triplet-center row + outlier row
//  - block 0 computes ||C C^T - I||_F^2 and adds sqrt of it
//  - all blocks grid-stride the MSE sum with 6x-unrolled float4 loads
//  - one atomicAdd(out) per block with fully-scaled contribution
__global__ void cae_fused_kernel(const float4* __restrict__ x,
                                 const float4* __restrict__ xh,
                                 const int*    __restrict__ target,
                                 const float*  __restrict__ z_in,
                                 const float*  __restrict__ z_out,
                                 const float*  __restrict__ center_arr,
                                 float* __restrict__ out,
                                 long n4, int B, int C, int L,
                                 float invBD, float invB) {
    extern __shared__ float smc[];          // C*L normalized centers
    __shared__ float sred[4];
    __shared__ float sorth;

    const int tid  = threadIdx.x;
    const int wave = tid >> 6;
    const int lane = tid & 63;
    const int epl  = L >> 6;                // 2 for L=128

    // ---- stage + normalize centers (waves handle rows strided) ----
    for (int c = wave; c < C; c += 4) {
        float e0 = center_arr[c * L + lane * epl + 0];
        float e1 = center_arr[c * L + lane * epl + 1];
        float ss = waveReduceSum(e0 * e0 + e1 * e1);
        const float inv = rsqrtf(ss);
        smc[c * L + lane * epl + 0] = e0 * inv;
        smc[c * L + lane * epl + 1] = e1 * inv;
    }
    if (blockIdx.x == 0 && tid == 0) sorth = 0.f;
    __syncthreads();

    float v = 0.f;   // this thread's contribution (already scaled)

    // ---- triplet-center + outlier: one wave per row, blocks [0, B/4) ----
    const int row = blockIdx.x * 4 + wave;
    if (row < B) {
        const float zi0 = z_in[row * L + lane * epl + 0];
        const float zi1 = z_in[row * L + lane * epl + 1];
        const int tgt = target[row];
        float pos = 0.f, neg = INFINITY;
        for (int c = 0; c < C; ++c) {
            const float d0 = zi0 - smc[c * L + lane * epl + 0];
            const float d1 = zi1 - smc[c * L + lane * epl + 1];
            const float d2 = waveReduceSum(d0 * d0 + d1 * d1);
            const float dist = sqrtf(d2);
            if (c == tgt) pos = dist;
            else          neg = fminf(neg, dist);
        }
        const float zo0 = z_out[row * L + lane * epl + 0];
        const float zo1 = z_out[row * L + lane * epl + 1];
        const float zo2 = waveReduceSum(zo0 * zo0 + zo1 * zo1);
        if (lane == 0) {
            const float tc = fmaxf(pos + D_IN_M - neg, 0.f);
            const float ol = fmaxf(D_OUT_M - sqrtf(zo2), 0.f);
            v += (tc + ol) * invB;
        }
    }

    // ---- orthogonality (block 0 only): gram rows strided over waves ----
    if (blockIdx.x == 0) {
        float part = 0.f;
        for (int r = wave; r < C; r += 4) {
            const float a0 = smc[r * L + lane * epl + 0];
            const float a1 = smc[r * L + lane * epl + 1];
            for (int cc = 0; cc < C; ++cc) {
                const float d = waveReduceSum(
                    a0 * smc[cc * L + lane * epl + 0] +
                    a1 * smc[cc * L + lane * epl + 1]);
                const float t = d - (cc == r ? 1.f : 0.f);
                part += t * t;
            }
        }
        if (lane == 0) atomicAdd(&sorth, part);
    }

    // ---- MSE: grid-stride, 6x unrolled (exactly one batch for 4096x3072) ----
    {
        const long stride = (long)gridDim.x * blockDim.x;
        long i = (long)blockIdx.x * blockDim.x + tid;
        float acc = 0.f;
        for (; i + 5 * stride < n4; i += 6 * stride) {
            const float4 a0 = x[i];
            const float4 a1 = x[i + stride];
            const float4 a2 = x[i + 2 * stride];
            const float4 a3 = x[i + 3 * stride];
            const float4 a4 = x[i + 4 * stride];
            const float4 a5 = x[i + 5 * stride];
            const float4 b0 = xh[i];
            const float4 b1 = xh[i + stride];
            const float4 b2 = xh[i + 2 * stride];
            const float4 b3 = xh[i + 3 * stride];
            const float4 b4 = xh[i + 4 * stride];
            const float4 b5 = xh[i + 5 * stride];
            float d;
            d = a0.x - b0.x; acc += d * d; d = a0.y - b0.y; acc += d * d;
            d = a0.z - b0.z; acc += d * d; d = a0.w - b0.w; acc += d * d;
            d = a1.x - b1.x; acc += d * d; d = a1.y - b1.y; acc += d * d;
            d = a1.z - b1.z; acc += d * d; d = a1.w - b1.w; acc += d * d;
            d = a2.x - b2.x; acc += d * d; d = a2.y - b2.y; acc += d * d;
            d = a2.z - b2.z; acc += d * d; d = a2.w - b2.w; acc += d * d;
            d = a3.x - b3.x; acc += d * d; d = a3.y - b3.y; acc += d * d;
            d = a3.z - b3.z; acc += d * d; d = a3.w - b3.w; acc += d * d;
            d = a4.x - b4.x; acc += d * d; d = a4.y - b4.y; acc += d * d;
            d = a4.z - b4.z; acc += d * d; d = a4.w - b4.w; acc += d * d;
            d = a5.x - b5.x; acc += d * d; d = a5.y - b5.y; acc += d * d;
            d = a5.z - b5.z; acc += d * d; d = a5.w - b5.w; acc += d * d;
        }
        for (; i < n4; i += stride) {           // remainder (not hit at 4096x3072)
            const float4 a = x[i], b = xh[i];
            float d;
            d = a.x - b.x; acc += d * d; d = a.y - b.y; acc += d * d;
            d = a.z - b.z; acc += d * d; d = a.w - b.w; acc += d * d;
        }
        v += acc * invBD;
    }

    // ---- block reduce + single atomicAdd ----
    v = waveReduceSum(v);
    if (lane == 0) sred[wave] = v;
    __syncthreads();
    if (tid == 0) {
        float s = sred[0] + sred[1] + sred[2] + sred[3];
        if (blockIdx.x == 0) s += sqrtf(sorth);
        atomicAdd(out, s);
    }
}

extern "C" void kernel_launch(void* const* d_in, const int* in_sizes, int n_in,
                              void* d_out, int out_size, void* d_ws, size_t ws_size,
                              hipStream_t stream) {
    const float* x          = (const float*)d_in[0];
    const float* x_hat      = (const float*)d_in[1];
    const int*   target     = (const int*)d_in[2];
    const float* z_in       = (const float*)d_in[3];
    const float* z_out      = (const float*)d_in[4];
    const float* center_arr = (const float*)d_in[5];
    float* out = (float*)d_out;

    const int B = in_sizes[2];
    const int D = in_sizes[0] / B;
    const int L = in_sizes[3] / B;
    const int C = in_sizes[5] / L;
    const long n4 = (long)B * D / 4;

    hipMemsetAsync(d_out, 0, sizeof(float), stream);

    cae_fused_kernel<<<2048, 256, C * L * sizeof(float), stream>>>(
        (const float4*)x, (const float4*)x_hat, target, z_in, z_out, center_arr,
        out, n4, B, C, L, 1.f / ((float)B * D), 1.f / (float)B);
}